// Round 10
// baseline (364.098 us; speedup 1.0000x reference)
//
#include <hip/hip_runtime.h>
#include <hip/hip_bf16.h>
#include <stdint.h>

using bf16 = __hip_bfloat16;
typedef __bf16 bf16x8 __attribute__((ext_vector_type(8)));
typedef float f32x4 __attribute__((ext_vector_type(4)));
typedef unsigned short u16x8 __attribute__((ext_vector_type(8)));

#define GLOAD_LDS16(gp, lp)                                                    \
  __builtin_amdgcn_global_load_lds(                                           \
      (const __attribute__((address_space(1))) void*)(gp),                     \
      (__attribute__((address_space(3))) void*)(lp), 16, 0, 0)

#define WAITCNT_VM(N) asm volatile("s_waitcnt vmcnt(" #N ")" ::: "memory")
#define SB0() __builtin_amdgcn_sched_barrier(0)

__device__ inline void store_out(bf16* p, float v)  { *p = __float2bfloat16(v); }
__device__ inline void store_out(float* p, float v) { *p = v; }

// ---------------------------------------------------------------------------
// NT GEMM, 128x128 tile, BK=32, ring-3 LDS (48 KB -> 3 blocks/CU), counted
// vmcnt (T4), conflict-free swizzled LDS (T2), T1 chunked-XCD swizzle.
// Occupancy ladder (measured): 1 blk/CU (any schedule) = ~700 TF; 2 blk/CU
// (256x128 ring-3) = 818 TF; this round: 3 blk/CU -- cross-block phase
// interleave (m114) is the only lever that has moved MfmaUtil.
// 256 thr = 4 waves (2M x 2N), per-wave 64x64 out (4x4 frags 16x16x32,
// 64 AGPR + ~40 VGPR -> under the 128-VGPR/16-wave occupancy cliff).
// C[m][n] = alpha * sum_k A[m][k]*Bt[n][k] (+bias). Col-split epilogue.
// BIAS_AXIS: 0 per-col, 1 per-row. M,N mult 128, K mult 32 (>=128).
//
// LDS: 3 ring slots x 8192 elems (A 128x32 at +0, B 128x32 at +4096).
// Chunk (16B): row r, chunk col c (0..3) stored at c ^ ((r>>1)&3); read
// elem(r,c16) = r*32 + ((c16 ^ ((r>>1)&3))*8  [same involution as round 9,
// measured 0 bank conflicts]. Stage: thread t writes chunks {t, t+256} of A
// and of B linearly (wave-uniform base + lane*16), src col pre-swizzled.
//
// Sync per step j: [8 ds_read_b128 (slot j%3); stage tile j+2 (4 gloads);
// 16 MFMA; vmcnt(4); s_barrier]. RAW: outstanding at step end = st(j+1) 4 +
// st(j+2) 4; vmcnt(4) drains st(j+1) -> resident after barrier. WAR:
// st(j+2) targets slot (j-1)%3 whose reads were consumed by step j-1 MFMAs
// (compiler lgkm waits) before its closing barrier. Tail: vmcnt(0)/none.
// ---------------------------------------------------------------------------
template <typename OUT_T, int BIAS_AXIS, bool NFAST>
__global__ __launch_bounds__(256, 3) void gemm_bm(
    const bf16* __restrict__ A, const bf16* __restrict__ Bt,
    const float* __restrict__ bias0, const float* __restrict__ bias1,
    OUT_T* __restrict__ out0, OUT_T* __restrict__ out1, int Nsplit,
    int K, int lda, int ldb, int ldc,
    long long sA, long long sB, long long sC, float alpha)
{
    __shared__ __align__(16) bf16 lds[24576];   // 48 KB: 3 x (4096 A + 4096 B)

    // ---- T1: chunked XCD swizzle + logical tile decode
    const int Mt = gridDim.x, Nt = gridDim.y;
    const int nwg = Mt * Nt * gridDim.z;
    const int hw  = blockIdx.x + Mt * (blockIdx.y + Nt * blockIdx.z);
    const int lg  = (nwg & 7) ? hw : ((hw & 7) * (nwg >> 3) + (hw >> 3));
    const int per = Mt * Nt;
    const int zt  = lg / per;
    const int rem = lg - zt * per;
    int mt, nt;
    if (NFAST) { mt = rem / Nt; nt = rem - mt * Nt; }
    else       { mt = rem % Mt; nt = rem / Mt; }

    A  += (long long)zt * sA;
    Bt += (long long)zt * sB;
    out0 += (long long)zt * sC;
    if (out1) out1 += (long long)zt * sC;

    const int bm = mt * 128;
    const int bn = nt * 128;
    const int t = threadIdx.x, lane = t & 63, w = t >> 6;
    const int wm = w >> 1, wn = w & 1;            // wave grid 2M x 2N
    const int fr = lane & 15, c16 = lane >> 4;

    // ---- staging src pointers: A chunks {t, t+256}, B chunks {t, t+256}
    const bf16* gA[2];
    const bf16* gB[2];
    #pragma unroll
    for (int k = 0; k < 2; ++k) {
        const int idx = t + 256 * k, r = idx >> 2, c = idx & 3;
        const int cs = (c ^ ((r >> 1) & 3)) << 3;
        gA[k] = A  + (long long)(bm + r) * lda + cs;
        gB[k] = Bt + (long long)(bn + r) * ldb + cs;
    }
    const int dstA = t * 8;            // chunk t -> elem t*8; +2048 for t+256
    const int dstB = 4096 + t * 8;

#define STAGE(JT, SLOTB) do {                                                  \
    GLOAD_LDS16(gA[0] + (JT) * 32, &lds[(SLOTB) + dstA]);                      \
    GLOAD_LDS16(gA[1] + (JT) * 32, &lds[(SLOTB) + dstA + 2048]);               \
    GLOAD_LDS16(gB[0] + (JT) * 32, &lds[(SLOTB) + dstB]);                      \
    GLOAD_LDS16(gB[1] + (JT) * 32, &lds[(SLOTB) + dstB + 2048]);               \
} while (0)

    // ---- fragment read offsets (elements), swizzled (same family as r9: 0cf)
    const int swz8 = (c16 ^ ((fr >> 1) & 3)) << 3;
    const int offA = (wm * 64 + fr) * 32 + swz8;          // + m*512
    const int offB = 4096 + (wn * 64 + fr) * 32 + swz8;   // + n*512

    const int nk = K >> 5;

    // prologue: stage tiles 0,1; drain tile 0 (keep tile 1's 4 in flight)
    STAGE(0, 0); STAGE(1, 8192);
    WAITCNT_VM(4);
    __builtin_amdgcn_s_barrier();

    f32x4 acc[4][4] = {};

    int slotb = 0;
    for (int j = 0; j < nk; ++j) {
        SB0();   // region open

        bf16x8 af[4], bfv[4];
        #pragma unroll
        for (int m = 0; m < 4; ++m)
            af[m] = *reinterpret_cast<const bf16x8*>(&lds[slotb + offA + m * 512]);
        #pragma unroll
        for (int n = 0; n < 4; ++n)
            bfv[n] = *reinterpret_cast<const bf16x8*>(&lds[slotb + offB + n * 512]);

        if (j + 2 < nk) {
            int s2 = slotb + 16384; if (s2 >= 24576) s2 -= 24576;
            STAGE(j + 2, s2);
        }

        #pragma unroll
        for (int m = 0; m < 4; ++m)
            #pragma unroll
            for (int n = 0; n < 4; ++n)
                acc[m][n] = __builtin_amdgcn_mfma_f32_16x16x32_bf16(
                    af[m], bfv[n], acc[m][n], 0, 0, 0);

        SB0();   // region close
        if (j + 2 < nk)      { WAITCNT_VM(4); }
        else if (j + 1 < nk) { WAITCNT_VM(0); }
        __builtin_amdgcn_s_barrier();

        slotb += 8192; if (slotb == 24576) slotb = 0;
    }

    // ---- epilogue: C/D layout col = lane&15, row = 4*(lane>>4)+reg
    const int colbase = bn + wn * 64 + fr;
    const int rowbase = bm + wm * 64 + c16 * 4;
    #pragma unroll
    for (int n = 0; n < 4; ++n) {
        const int gc = colbase + n * 16;
        const bool seg0 = gc < Nsplit;
        OUT_T* op = seg0 ? out0 : out1;
        const int col = seg0 ? gc : gc - Nsplit;
        float bcol = 0.0f;
        if (BIAS_AXIS == 0) {
            const float* bp = seg0 ? bias0 : bias1;
            if (bp) bcol = bp[col];
        }
        #pragma unroll
        for (int m = 0; m < 4; ++m) {
            #pragma unroll
            for (int jj = 0; jj < 4; ++jj) {
                const int row = rowbase + m * 16 + jj;
                float v = acc[m][n][jj] * alpha;
                if (BIAS_AXIS == 0) v += bcol;
                else if (bias0)     v += bias0[row];
                store_out(&op[(long long)row * ldc + col], v);
            }
        }
    }
#undef STAGE
}

// ---------------------------------------------------------------------------
// fp32 -> bf16 elementwise convert (n multiple of 4)
// ---------------------------------------------------------------------------
__global__ __launch_bounds__(256) void f32_to_bf16(
    const float* __restrict__ in, bf16* __restrict__ out, long long n)
{
    long long i = ((long long)blockIdx.x * 256 + threadIdx.x) * 4;
    const long long stride = (long long)gridDim.x * 256 * 4;
    for (; i < n; i += stride) {
        float4 v = *reinterpret_cast<const float4*>(in + i);
        unsigned ux = __float_as_uint(v.x), uy = __float_as_uint(v.y);
        unsigned uz = __float_as_uint(v.z), uw = __float_as_uint(v.w);
        ushort4 o;
        o.x = (unsigned short)((ux + 0x7fffu + ((ux >> 16) & 1u)) >> 16);
        o.y = (unsigned short)((uy + 0x7fffu + ((uy >> 16) & 1u)) >> 16);
        o.z = (unsigned short)((uz + 0x7fffu + ((uz >> 16) & 1u)) >> 16);
        o.w = (unsigned short)((uw + 0x7fffu + ((uw >> 16) & 1u)) >> 16);
        *reinterpret_cast<ushort4*>(out + i) = o;
    }
}

// ---------------------------------------------------------------------------
// Transpose fp32 in [R][C] -> bf16 out [C][R]
// ---------------------------------------------------------------------------
__global__ void transpose_f32_bf16(const float* __restrict__ in,
                                   bf16* __restrict__ out, int R, int C)
{
    __shared__ float tile[32][33];
    const int c0 = blockIdx.x * 32, r0 = blockIdx.y * 32;
    const int tx = threadIdx.x, ty = threadIdx.y;
    #pragma unroll
    for (int i = ty; i < 32; i += 8)
        tile[i][tx] = in[(long long)(r0 + i) * C + (c0 + tx)];
    __syncthreads();
    #pragma unroll
    for (int i = ty; i < 32; i += 8)
        out[(long long)(c0 + i) * R + (r0 + tx)] = __float2bfloat16(tile[tx][i]);
}

// ---------------------------------------------------------------------------
// Row softmax, in-place on bf16 buffer, one 256-thread block per 2048-col row.
// ---------------------------------------------------------------------------
__global__ __launch_bounds__(256) void softmax_rows(bf16* __restrict__ Sbuf, int cols)
{
    __shared__ float red[8];
    bf16* p = Sbuf + (long long)blockIdx.x * cols;
    const int t = threadIdx.x;

    u16x8 v = *reinterpret_cast<const u16x8*>(p + t * 8);
    float f[8];
    #pragma unroll
    for (int i = 0; i < 8; ++i)
        f[i] = __uint_as_float((unsigned)v[i] << 16);

    float m = -3.0e38f;
    #pragma unroll
    for (int i = 0; i < 8; ++i) m = fmaxf(m, f[i]);
    #pragma unroll
    for (int o = 32; o; o >>= 1) m = fmaxf(m, __shfl_xor(m, o));
    if ((t & 63) == 0) red[t >> 6] = m;
    __syncthreads();
    m = fmaxf(fmaxf(red[0], red[1]), fmaxf(red[2], red[3]));

    float s = 0.0f;
    #pragma unroll
    for (int i = 0; i < 8; ++i) { f[i] = __expf(f[i] - m); s += f[i]; }
    #pragma unroll
    for (int o = 32; o; o >>= 1) s += __shfl_xor(s, o);
    __syncthreads();
    if ((t & 63) == 0) red[4 + (t >> 6)] = s;
    __syncthreads();
    s = (red[4] + red[5]) + (red[6] + red[7]);
    const float inv = 1.0f / s;

    u16x8 o16;
    #pragma unroll
    for (int i = 0; i < 8; ++i) {
        unsigned u = __float_as_uint(f[i] * inv);
        o16[i] = (unsigned short)((u + 0x7fffu + ((u >> 16) & 1u)) >> 16);  // RNE
    }
    *reinterpret_cast<u16x8*>(p + t * 8) = o16;
}

// ---------------------------------------------------------------------------
extern "C" void kernel_launch(void* const* d_in, const int* in_sizes, int n_in,
                              void* d_out, int out_size, void* d_ws, size_t ws_size,
                              hipStream_t stream)
{
    const int B = 8, S = 2048, D = 1024, H = 1024;
    const float* x  = (const float*)d_in[0];
    const float* Wq = (const float*)d_in[1];
    const float* bq = (const float*)d_in[2];
    const float* Wk = (const float*)d_in[3];
    const float* bk = (const float*)d_in[4];
    const float* Wv = (const float*)d_in[5];
    const float* bv = (const float*)d_in[6];
    float* out = (float*)d_out;

    const size_t nQKV = (size_t)B * S * H;
    const size_t nW   = (size_t)D * H;
    const long long sSH = (long long)S * H;
    const long long sSS = (long long)S * S;

    dim3 tb(32, 8), g256(256);
    const float inv_scale = 1.0f / 32.0f;    // 1/sqrt(H)

    // ws: xb | Q | K | Vt | WtQK(2nW) | Wtv(nW) | Sc
    bf16* xb   = (bf16*)d_ws;
    bf16* Q    = xb  + nQKV;
    bf16* Kb   = Q   + nQKV;
    bf16* Vt   = Kb  + nQKV;                 // [H][B*S], ld = B*S
    bf16* WtQK = Vt  + nQKV;
    bf16* Wtv  = WtQK + 2 * nW;
    bf16* Sc   = Wtv + nW;

    const size_t tierA = (4 * nQKV + 3 * nW + (size_t)B * S * S) * 2;
    const size_t tierB = (4 * nQKV + 3 * nW + (size_t)S * S) * 2;
    const bool bigA = ws_size >= tierA;
    if (ws_size < tierB) return;

    // 1. convert x; transpose weights
    f32_to_bf16<<<dim3(2048), g256, 0, stream>>>(x, xb, (long long)nQKV);
    transpose_f32_bf16<<<dim3(H / 32, D / 32), tb, 0, stream>>>(Wq, WtQK, D, H);
    transpose_f32_bf16<<<dim3(H / 32, D / 32), tb, 0, stream>>>(Wk, WtQK + nW, D, H);
    transpose_f32_bf16<<<dim3(H / 32, D / 32), tb, 0, stream>>>(Wv, Wtv, D, H);

    // 2. fused Q|K projection: [B*S,1024] x [2048,1024]^T -> Q, K (col-split)
    gemm_bm<bf16, 0, true><<<dim3(B * S / 128, 2 * H / 128, 1), g256, 0, stream>>>(
        xb, WtQK, bq, bk, Q, Kb, H, D, D, D, H, 0, 0, 0, 1.0f);

    // 3. V^T = Wv^T x^T : A=Wtv [H][D], Bt=xb [B*S][D] -> Vt [H][B*S], bias-by-row
    gemm_bm<bf16, 1, false><<<dim3(H / 128, B * S / 128, 1), g256, 0, stream>>>(
        Wtv, xb, bv, nullptr, Vt, nullptr, 1 << 30, D, D, D, B * S, 0, 0, 0, 1.0f);

    if (bigA) {
        // 4. scores = Q K^T / 32, batched
        gemm_bm<bf16, 0, true><<<dim3(S / 128, S / 128, B), g256, 0, stream>>>(
            Q, Kb, nullptr, nullptr, Sc, nullptr, 1 << 30, H, H, H, S,
            sSH, sSH, sSS, inv_scale);
        // 5. softmax rows in place
        softmax_rows<<<dim3(B * S), g256, 0, stream>>>(Sc, S);
        // 6. out = P V
        gemm_bm<float, 0, true><<<dim3(S / 128, H / 128, B), g256, 0, stream>>>(
            Sc, Vt, nullptr, nullptr, out, nullptr, 1 << 30, S, S, B * S, H,
            sSS, (long long)S, sSH, 1.0f);
    } else {
        for (int b = 0; b < B; ++b) {
            gemm_bm<bf16, 0, true><<<dim3(S / 128, S / 128, 1), g256, 0, stream>>>(
                Q + (size_t)b * sSH, Kb + (size_t)b * sSH, nullptr, nullptr,
                Sc, nullptr, 1 << 30, H, H, H, S, 0, 0, 0, inv_scale);
            softmax_rows<<<dim3(S), g256, 0, stream>>>(Sc, S);
            gemm_bm<float, 0, true><<<dim3(S / 128, H / 128, 1), g256, 0, stream>>>(
                Sc, Vt + (size_t)b * S, nullptr, nullptr,
                out + (size_t)b * sSH, nullptr, 1 << 30, S, S, B * S, H,
                0, 0, 0, 1.0f);
        }
    }
}